// Round 3
// baseline (127.804 us; speedup 1.0000x reference)
//
#include <hip/hip_runtime.h>
#include <hip/hip_bf16.h>
#include <math.h>

// SupConLoss, B=4096 V=2 D=128, N=8192.
// loss = (1/N) [ sum_i log(sum_{j!=i} exp(n_i.n_j/T)) - 2*sum_b spos_b ]
// Round 3: 2 dispatches. prep_k: normalize + per-block spos sums + zero tickets.
// main_k: bf16-MFMA GEMM + exp2 + row sums + ticket-based distributed finalize.

constexpr int   Bsz   = 4096;
constexpr int   Nrows = 8192;
constexpr int   Dd    = 128;
constexpr float TEMPf = 0.07f;
constexpr float EPSN  = 1e-8f;
constexpr float SCALE = 1.4426950408889634f / 0.07f;  // log2(e)/T
constexpr float LN2   = 0.6931471805599453f;

constexpr int CHUNKS     = 16;                     // column chunks (grid.x)
constexpr int CHUNK_COLS = Nrows / CHUNKS;         // 512
constexpr int TILE_COLS  = 32;
constexpr int TILES      = CHUNK_COLS / TILE_COLS; // 16
constexpr int YGROUPS    = Nrows / 256;            // 32 (grid.y)
constexpr int PREPBLKS   = Bsz / 4;                // 1024

typedef __attribute__((ext_vector_type(8)))  short bf16x8;   // 8 bf16 = 4 VGPRs
typedef __attribute__((ext_vector_type(16))) float floatx16; // MFMA 32x32 C/D

// ws layout (bytes):
//   0x000000  nB   bf16[8192][128]   2 MB
//   0x200000  nA   bf16[8192][128]   2 MB  (pre-scaled by SCALE)
//   0x400000  partial f32[16][8192]  512 KB
//   0x480000  sposPart f32[1024]     4 KB
//   0x481000  ylog f32[32]           128 B
//   0x481080  cnt  u32[33]           ycount[32] + done
constexpr size_t OFF_NA   = 0x200000;
constexpr size_t OFF_PART = 0x400000;
constexpr size_t OFF_SPOS = 0x480000;
constexpr size_t OFF_YLOG = 0x481000;
constexpr size_t OFF_CNT  = 0x481080;

// ------------- prep: normalize both views + per-block spos sums ----------------
// One wave per sample b (4 samples/block). view0 -> row b, view1 -> row Bsz+b.
__global__ void prep_k(const float* __restrict__ f,
                       __hip_bfloat16* __restrict__ nB,
                       __hip_bfloat16* __restrict__ nA,
                       float* __restrict__ sposPart,
                       unsigned int* __restrict__ cnt) {
    __shared__ float sred[4];
    int tid  = threadIdx.x;
    int wid  = tid >> 6;
    int lane = tid & 63;
    int b    = blockIdx.x * 4 + wid;
    if (blockIdx.x == 0 && tid < 33) cnt[tid] = 0;   // tickets zeroed each call

    const float* s0 = f + (size_t)(b * 2) * Dd;       // features[b, 0, :]
    float2 x = *(const float2*)(s0 + lane * 2);       // view 0
    float2 y = *(const float2*)(s0 + Dd + lane * 2);  // view 1
    float ss0 = x.x * x.x + x.y * x.y;
    float ss1 = y.x * y.x + y.y * y.y;
    float dt  = x.x * y.x + x.y * y.y;
    #pragma unroll
    for (int off = 32; off; off >>= 1) {
        ss0 += __shfl_xor(ss0, off);
        ss1 += __shfl_xor(ss1, off);
        dt  += __shfl_xor(dt,  off);
    }
    float inv0 = 1.0f / fmaxf(sqrtf(ss0), EPSN);
    float inv1 = 1.0f / fmaxf(sqrtf(ss1), EPSN);
    __hip_bfloat162 h;
    h.x = __float2bfloat16(x.x * inv0);
    h.y = __float2bfloat16(x.y * inv0);
    *(__hip_bfloat162*)(nB + (size_t)b * Dd + lane * 2) = h;
    h.x = __float2bfloat16(x.x * inv0 * SCALE);
    h.y = __float2bfloat16(x.y * inv0 * SCALE);
    *(__hip_bfloat162*)(nA + (size_t)b * Dd + lane * 2) = h;
    h.x = __float2bfloat16(y.x * inv1);
    h.y = __float2bfloat16(y.y * inv1);
    *(__hip_bfloat162*)(nB + (size_t)(Bsz + b) * Dd + lane * 2) = h;
    h.x = __float2bfloat16(y.x * inv1 * SCALE);
    h.y = __float2bfloat16(y.y * inv1 * SCALE);
    *(__hip_bfloat162*)(nA + (size_t)(Bsz + b) * Dd + lane * 2) = h;

    if (lane == 0) sred[wid] = dt * inv0 * inv1 / TEMPf;
    __syncthreads();
    if (tid == 0) sposPart[blockIdx.x] = sred[0] + sred[1] + sred[2] + sred[3];
}

// ------------- main: fused nA·nB^T -> exp2 -> row sums -> finalize -------------
// Block: 256 thr (4 waves). Wave tile: 64 rows x 32 cols, K=128.
// A in registers; B tile in 8 KB LDS, [k-unit][col] XOR-swizzled (conflict-free).
// Ticket finalize: last x-block per y-group log-reduces its 256 rows; last of
// the 32 y-groups sums ylog + sposPart and writes the scalar loss.
__global__ __launch_bounds__(256, 2)
void main_k(const __hip_bfloat16* __restrict__ nA, const __hip_bfloat16* __restrict__ nB,
            float* __restrict__ partial, const float* __restrict__ sposPart,
            float* __restrict__ ylog, unsigned int* __restrict__ cnt,
            float* __restrict__ out) {
    __shared__ char lds[TILE_COLS * 256];   // 8 KB: 16 units x 32 cols x 16 B
    const int tid  = threadIdx.x;
    const int wid  = tid >> 6;
    const int lane = tid & 63;
    const int lo   = lane & 31;
    const int hi   = lane >> 5;
    const int rbase = blockIdx.y * 256 + wid * 64;   // wave's 64 rows
    const int cbase = blockIdx.x * CHUNK_COLS;
    const char* abytes = (const char*)nA;            // 256 B per row
    const char* bbytes = (const char*)nB;

    // A fragments: row = rbase + s*32 + lo, k-bytes = kc*32 + hi*16
    bf16x8 afrag[2][8];
    #pragma unroll
    for (int s = 0; s < 2; s++) {
        const char* rowp = abytes + (size_t)(rbase + s * 32 + lo) * 256 + hi * 16;
        #pragma unroll
        for (int kc = 0; kc < 8; kc++)
            afrag[s][kc] = *(const bf16x8*)(rowp + kc * 32);
    }

    float sums[2][16];
    #pragma unroll
    for (int s = 0; s < 2; s++)
        #pragma unroll
        for (int r = 0; r < 16; r++) sums[s][r] = 0.f;

    floatx16 zero = {};

    for (int t = 0; t < TILES; t++) {
        const int tc = cbase + t * TILE_COLS;
        __syncthreads();
        {   // stage B tile: thread t -> col c = t>>3, 32 B part = t&7 (coalesced)
            int c = tid >> 3, part = tid & 7;
            const char* g = bbytes + (size_t)(tc + c) * 256 + part * 32;
            uint4 g0 = *(const uint4*)g;
            uint4 g1 = *(const uint4*)(g + 16);
            int u0 = part * 2, u1 = u0 + 1;
            *(uint4*)&lds[u0 * 512 + ((c ^ u0) & 31) * 16] = g0;
            *(uint4*)&lds[u1 * 512 + ((c ^ u1) & 31) * 16] = g1;
        }
        __syncthreads();

        floatx16 acc0 = zero, acc1 = zero;
        #pragma unroll
        for (int kc = 0; kc < 8; kc++) {
            int u = kc * 2 + hi;
            bf16x8 bfrag = *(const bf16x8*)&lds[u * 512 + ((lo ^ u) & 31) * 16];
            acc0 = __builtin_amdgcn_mfma_f32_32x32x16_bf16(afrag[0][kc], bfrag, acc0, 0, 0, 0);
            acc1 = __builtin_amdgcn_mfma_f32_32x32x16_bf16(afrag[1][kc], bfrag, acc1, 0, 0, 0);
        }

        // epilogue: e = exp2(acc) (SCALE pre-folded into A), mask diag, accumulate
        #pragma unroll
        for (int s = 0; s < 2; s++) {
            const floatx16& acc = s ? acc1 : acc0;
            bool dtile = (tc == rbase + s * 32);   // wave-uniform, true <=1 time
            #pragma unroll
            for (int r = 0; r < 16; r++) {
                float e = __builtin_amdgcn_exp2f(acc[r]);
                // C/D layout (m74/m101): col=lo, row=(r&3)+8*(r>>2)+4*hi
                if (dtile && lo == ((r & 3) + 8 * (r >> 2) + 4 * hi)) e = 0.f;
                sums[s][r] += e;
            }
        }
    }

    // reduce across the 32 lanes (cols) sharing hi; store per-chunk partials
    #pragma unroll
    for (int s = 0; s < 2; s++)
        #pragma unroll
        for (int r = 0; r < 16; r++) {
            float v = sums[s][r];
            #pragma unroll
            for (int off = 1; off < 32; off <<= 1) v += __shfl_xor(v, off);
            sums[s][r] = v;
        }
    if (lo == 0) {
        float* prow = partial + (size_t)blockIdx.x * Nrows;
        #pragma unroll
        for (int s = 0; s < 2; s++)
            #pragma unroll
            for (int r = 0; r < 16; r++) {
                int grow = rbase + s * 32 + (r & 3) + 8 * (r >> 2) + 4 * hi;
                prow[grow] = sums[s][r];
            }
    }

    // ---------------- ticket finalize ----------------
    __shared__ int tick, t2s;
    __shared__ float red[4];
    __threadfence();                                  // release partial stores
    if (tid == 0) tick = (int)atomicAdd(&cnt[blockIdx.y], 1u);
    __syncthreads();
    if (tick == CHUNKS - 1) {                         // last x-block for this y
        __threadfence();                              // acquire others' partials
        int row = blockIdx.y * 256 + tid;
        float se = 0.f;
        #pragma unroll
        for (int c = 0; c < CHUNKS; c++) se += partial[(size_t)c * Nrows + row];
        float lv = __builtin_amdgcn_logf(se) * LN2;   // v_log_f32 is log2
        #pragma unroll
        for (int off = 32; off; off >>= 1) lv += __shfl_xor(lv, off);
        if (lane == 0) red[wid] = lv;
        __syncthreads();
        if (tid == 0) {
            ylog[blockIdx.y] = red[0] + red[1] + red[2] + red[3];
            __threadfence();                          // release ylog
            t2s = (int)atomicAdd(&cnt[32], 1u);
        }
        __syncthreads();
        if (t2s == YGROUPS - 1) {                     // very last y-group
            __threadfence();                          // acquire all ylog
            float a = 0.f;
            if (tid < YGROUPS) a += ylog[tid];
            for (int i = tid; i < PREPBLKS; i += 256) a -= 2.f * sposPart[i];
            #pragma unroll
            for (int off = 32; off; off >>= 1) a += __shfl_xor(a, off);
            if (lane == 0) red[wid] = a;
            __syncthreads();
            if (tid == 0)
                out[0] = (red[0] + red[1] + red[2] + red[3]) / (float)Nrows;
        }
    }
}

extern "C" void kernel_launch(void* const* d_in, const int* in_sizes, int n_in,
                              void* d_out, int out_size, void* d_ws, size_t ws_size,
                              hipStream_t stream) {
    const float* f = (const float*)d_in[0];
    char* ws = (char*)d_ws;
    __hip_bfloat16* nB = (__hip_bfloat16*)ws;
    __hip_bfloat16* nA = (__hip_bfloat16*)(ws + OFF_NA);
    float* partial     = (float*)(ws + OFF_PART);
    float* sposPart    = (float*)(ws + OFF_SPOS);
    float* ylog        = (float*)(ws + OFF_YLOG);
    unsigned int* cnt  = (unsigned int*)(ws + OFF_CNT);

    prep_k<<<PREPBLKS, 256, 0, stream>>>(f, nB, nA, sposPart, cnt);
    dim3 grid(CHUNKS, YGROUPS);
    main_k<<<grid, 256, 0, stream>>>(nA, nB, partial, sposPart, ylog, cnt,
                                     (float*)d_out);
}

// Round 4
// 87.693 us; speedup vs baseline: 1.4574x; 1.4574x over previous
//
#include <hip/hip_runtime.h>
#include <hip/hip_bf16.h>
#include <math.h>

// SupConLoss, B=4096 V=2 D=128, N=8192.
// loss = (1/N) [ sum_i log(sum_{j!=i} exp(n_i.n_j/T)) - 2*sum_b spos_b ]
// Round 4: back to 3 dispatches (NO device-scope fences — R3 showed +50us).
// main_k: 64-col tiles, double-buffered LDS, VGPR prefetch, ONE barrier/tile.

constexpr int   Bsz   = 4096;
constexpr int   Nrows = 8192;
constexpr int   Dd    = 128;
constexpr float TEMPf = 0.07f;
constexpr float EPSN  = 1e-8f;
constexpr float SCALE = 1.4426950408889634f / 0.07f;  // log2(e)/T
constexpr float LN2   = 0.6931471805599453f;

constexpr int CHUNKS     = 16;                     // column chunks (grid.x)
constexpr int CHUNK_COLS = Nrows / CHUNKS;         // 512
constexpr int TILE_COLS  = 64;
constexpr int TILES      = CHUNK_COLS / TILE_COLS; // 8
constexpr int YGROUPS    = Nrows / 256;            // 32 (grid.y)
constexpr int PREPBLKS   = Bsz / 4;                // 1024
constexpr int TILE_BYTES = TILE_COLS * 256;        // 16 KB

typedef __attribute__((ext_vector_type(8)))  short bf16x8;   // 8 bf16 = 4 VGPRs
typedef __attribute__((ext_vector_type(16))) float floatx16; // MFMA 32x32 C/D

// ws layout (bytes):
//   0x000000  nB   bf16[8192][128]   2 MB
//   0x200000  nA   bf16[8192][128]   2 MB  (pre-scaled by SCALE)
//   0x400000  partial f32[16][8192]  512 KB
//   0x480000  sposPart f32[1024]     4 KB
constexpr size_t OFF_NA   = 0x200000;
constexpr size_t OFF_PART = 0x400000;
constexpr size_t OFF_SPOS = 0x480000;

// ------------- prep: normalize both views + per-block spos sums ----------------
// One wave per sample b (4/block). view0 -> row b, view1 -> row Bsz+b.
__global__ void prep_k(const float* __restrict__ f,
                       __hip_bfloat16* __restrict__ nB,
                       __hip_bfloat16* __restrict__ nA,
                       float* __restrict__ sposPart) {
    __shared__ float sred[4];
    int tid  = threadIdx.x;
    int wid  = tid >> 6;
    int lane = tid & 63;
    int b    = blockIdx.x * 4 + wid;

    const float* s0 = f + (size_t)(b * 2) * Dd;       // features[b, 0, :]
    float2 x = *(const float2*)(s0 + lane * 2);       // view 0
    float2 y = *(const float2*)(s0 + Dd + lane * 2);  // view 1
    float ss0 = x.x * x.x + x.y * x.y;
    float ss1 = y.x * y.x + y.y * y.y;
    float dt  = x.x * y.x + x.y * y.y;
    #pragma unroll
    for (int off = 32; off; off >>= 1) {
        ss0 += __shfl_xor(ss0, off);
        ss1 += __shfl_xor(ss1, off);
        dt  += __shfl_xor(dt,  off);
    }
    float inv0 = 1.0f / fmaxf(sqrtf(ss0), EPSN);
    float inv1 = 1.0f / fmaxf(sqrtf(ss1), EPSN);
    __hip_bfloat162 h;
    h.x = __float2bfloat16(x.x * inv0);
    h.y = __float2bfloat16(x.y * inv0);
    *(__hip_bfloat162*)(nB + (size_t)b * Dd + lane * 2) = h;
    h.x = __float2bfloat16(x.x * inv0 * SCALE);
    h.y = __float2bfloat16(x.y * inv0 * SCALE);
    *(__hip_bfloat162*)(nA + (size_t)b * Dd + lane * 2) = h;
    h.x = __float2bfloat16(y.x * inv1);
    h.y = __float2bfloat16(y.y * inv1);
    *(__hip_bfloat162*)(nB + (size_t)(Bsz + b) * Dd + lane * 2) = h;
    h.x = __float2bfloat16(y.x * inv1 * SCALE);
    h.y = __float2bfloat16(y.y * inv1 * SCALE);
    *(__hip_bfloat162*)(nA + (size_t)(Bsz + b) * Dd + lane * 2) = h;

    if (lane == 0) sred[wid] = dt * inv0 * inv1 / TEMPf;
    __syncthreads();
    if (tid == 0) sposPart[blockIdx.x] = sred[0] + sred[1] + sred[2] + sred[3];
}

// ------------- main: fused nA·nB^T -> exp2 -> per-chunk row sums ---------------
// Block: 256 thr (4 waves). Wave tile: 64 rows x 64 cols, K=128.
// A (64 rows x 128, pre-scaled) in regs; B tile (64 cols x 256 B = 16 KB)
// double-buffered in LDS, layout [u][cXORu] (b128 reads conflict-minimal).
// Prefetch t+1 into VGPRs during compute of t; ONE __syncthreads per tile.
__global__ __launch_bounds__(256, 2)
void main_k(const __hip_bfloat16* __restrict__ nA, const __hip_bfloat16* __restrict__ nB,
            float* __restrict__ partial) {
    __shared__ char lds[2][TILE_BYTES];   // 32 KB
    const int tid  = threadIdx.x;
    const int wid  = tid >> 6;
    const int lane = tid & 63;
    const int lo   = lane & 31;
    const int hi   = lane >> 5;
    const int rbase = blockIdx.y * 256 + wid * 64;   // wave's 64 rows
    const int cbase = blockIdx.x * CHUNK_COLS;
    const char* abytes = (const char*)nA;            // 256 B per row
    const char* gb     = (const char*)nB + (size_t)cbase * 256;  // chunk base
    const int su = tid & 15, scb = tid >> 4;         // staging u / col-quad

    // prefetch tile 0 (flat-contiguous: 4 x 16 B per thread, fully coalesced)
    uint4 pf[4];
    #pragma unroll
    for (int i = 0; i < 4; i++)
        pf[i] = *(const uint4*)(gb + i * 4096 + tid * 16);

    // A fragments: row = rbase + s*32 + lo, k-bytes = kc*32 + hi*16
    bf16x8 afrag[2][8];
    #pragma unroll
    for (int s = 0; s < 2; s++) {
        const char* rowp = abytes + (size_t)(rbase + s * 32 + lo) * 256 + hi * 16;
        #pragma unroll
        for (int kc = 0; kc < 8; kc++)
            afrag[s][kc] = *(const bf16x8*)(rowp + kc * 32);
    }

    // write tile 0: flat f = i*4096 + tid*16 -> c = i*16 + tid/16, u = tid&15
    #pragma unroll
    for (int i = 0; i < 4; i++) {
        int c = i * 16 + scb;
        *(uint4*)&lds[0][su * 1024 + ((c ^ su) & 63) * 16] = pf[i];
    }
    __syncthreads();

    float sums[2][16];
    #pragma unroll
    for (int s = 0; s < 2; s++)
        #pragma unroll
        for (int r = 0; r < 16; r++) sums[s][r] = 0.f;

    floatx16 zero = {};

    for (int t = 0; t < TILES; t++) {
        if (t + 1 < TILES) {          // prefetch next tile into VGPRs
            const char* g = gb + (size_t)(t + 1) * TILE_BYTES;
            #pragma unroll
            for (int i = 0; i < 4; i++)
                pf[i] = *(const uint4*)(g + i * 4096 + tid * 16);
        }

        const char* buf = lds[t & 1];
        floatx16 acc[2][2];           // [s row-half][cg col-group]
        acc[0][0] = zero; acc[0][1] = zero; acc[1][0] = zero; acc[1][1] = zero;
        #pragma unroll
        for (int kc = 0; kc < 8; kc++) {
            int u = kc * 2 + hi;
            int a0 = u * 1024 + ((lo ^ u) & 63) * 16;
            bf16x8 b0 = *(const bf16x8*)&buf[a0];        // cols cg=0 (lo)
            bf16x8 b1 = *(const bf16x8*)&buf[a0 ^ 512];  // cols cg=1 (lo+32)
            acc[0][0] = __builtin_amdgcn_mfma_f32_32x32x16_bf16(afrag[0][kc], b0, acc[0][0], 0, 0, 0);
            acc[1][0] = __builtin_amdgcn_mfma_f32_32x32x16_bf16(afrag[1][kc], b0, acc[1][0], 0, 0, 0);
            acc[0][1] = __builtin_amdgcn_mfma_f32_32x32x16_bf16(afrag[0][kc], b1, acc[0][1], 0, 0, 0);
            acc[1][1] = __builtin_amdgcn_mfma_f32_32x32x16_bf16(afrag[1][kc], b1, acc[1][1], 0, 0, 0);
        }

        // epilogue: exp2 (SCALE folded into A), diagonal mask, row-sum accumulate
        bool dtile = (cbase + t * TILE_COLS == rbase);   // both 64-aligned
        #pragma unroll
        for (int s = 0; s < 2; s++)
            #pragma unroll
            for (int cg = 0; cg < 2; cg++) {
                #pragma unroll
                for (int r = 0; r < 16; r++) {
                    float e = __builtin_amdgcn_exp2f(acc[s][cg][r]);
                    // C/D layout (m74/m101): col=cg*32+lo, row=s*32+(r&3)+8*(r>>2)+4*hi
                    if (dtile && cg == s && lo == ((r & 3) + 8 * (r >> 2) + 4 * hi))
                        e = 0.f;
                    sums[s][r] += e;
                }
            }

        if (t + 1 < TILES) {          // write prefetched tile to other buffer
            char* wb = lds[(t + 1) & 1];
            #pragma unroll
            for (int i = 0; i < 4; i++) {
                int c = i * 16 + scb;
                *(uint4*)&wb[su * 1024 + ((c ^ su) & 63) * 16] = pf[i];
            }
        }
        __syncthreads();   // writes visible for t+1; separates read epochs
    }

    // reduce across the 32 lanes (cols) sharing hi; store per-chunk partials
    #pragma unroll
    for (int s = 0; s < 2; s++)
        #pragma unroll
        for (int r = 0; r < 16; r++) {
            float v = sums[s][r];
            #pragma unroll
            for (int off = 1; off < 32; off <<= 1) v += __shfl_xor(v, off);
            sums[s][r] = v;
        }
    if (lo == 0) {
        float* prow = partial + (size_t)blockIdx.x * Nrows;
        #pragma unroll
        for (int s = 0; s < 2; s++)
            #pragma unroll
            for (int r = 0; r < 16; r++) {
                int grow = rbase + s * 32 + (r & 3) + 8 * (r >> 2) + 4 * hi;
                prow[grow] = sums[s][r];
            }
    }
}

// ------------- finalize: loss = (sum log(se) - 2*sum spos)/N -------------------
__global__ __launch_bounds__(1024)
void final_k(const float* __restrict__ partial, const float* __restrict__ sposPart,
             float* __restrict__ out) {
    __shared__ float red[16];
    int tid = threadIdx.x;   // 1024 threads
    float acc = 0.f;
    for (int r = tid; r < Nrows; r += 1024) {
        float se = 0.f;
        #pragma unroll
        for (int c = 0; c < CHUNKS; c++) se += partial[(size_t)c * Nrows + r];
        acc += __builtin_amdgcn_logf(se) * LN2;   // v_log_f32 is log2
    }
    for (int i = tid; i < PREPBLKS; i += 1024) acc -= 2.f * sposPart[i];
    #pragma unroll
    for (int off = 32; off; off >>= 1) acc += __shfl_xor(acc, off);
    if ((tid & 63) == 0) red[tid >> 6] = acc;
    __syncthreads();
    if (tid == 0) {
        float tt = 0.f;
        for (int w = 0; w < 16; w++) tt += red[w];
        out[0] = tt / (float)Nrows;
    }
}

extern "C" void kernel_launch(void* const* d_in, const int* in_sizes, int n_in,
                              void* d_out, int out_size, void* d_ws, size_t ws_size,
                              hipStream_t stream) {
    const float* f = (const float*)d_in[0];
    char* ws = (char*)d_ws;
    __hip_bfloat16* nB = (__hip_bfloat16*)ws;
    __hip_bfloat16* nA = (__hip_bfloat16*)(ws + OFF_NA);
    float* partial     = (float*)(ws + OFF_PART);
    float* sposPart    = (float*)(ws + OFF_SPOS);

    prep_k<<<PREPBLKS, 256, 0, stream>>>(f, nB, nA, sposPart);
    dim3 grid(CHUNKS, YGROUPS);
    main_k<<<grid, 256, 0, stream>>>(nA, nB, partial);
    final_k<<<1, 1024, 0, stream>>>(partial, sposPart, (float*)d_out);
}